// Round 7
// baseline (92.253 us; speedup 1.0000x reference)
//
#include <hip/hip_runtime.h>
#include <math.h>

#define NSTEPS 128
#define HID 64
#define RAYS_PER_BLOCK 8
#define THREADS_PER_RAY 32
#define SPT 4   // samples per thread

// Packed-f16 ops via inline asm (VOP3P), f32 accumulate via v_dot2_f32_f16.
static __device__ __forceinline__ unsigned pk_bits(float a, float b) {
    auto v = __builtin_amdgcn_cvt_pkrtz(a, b);   // v_cvt_pkrtz_f16_f32
    return __builtin_bit_cast(unsigned, v);
}
static __device__ __forceinline__ unsigned pk_fma(unsigned a, unsigned b, unsigned c) {
    unsigned d;
    asm("v_pk_fma_f16 %0, %1, %2, %3" : "=v"(d) : "v"(a), "v"(b), "v"(c));
    return d;
}
static __device__ __forceinline__ unsigned pk_relu(unsigned a) {
    unsigned d;
    asm("v_pk_max_f16 %0, %1, 0" : "=v"(d) : "v"(a));
    return d;
}
static __device__ __forceinline__ float dot2acc(unsigned h, unsigned w, float acc) {
    float d;
    asm("v_dot2_f32_f16 %0, %1, %2, %3" : "=v"(d) : "v"(h), "v"(w), "v"(acc));
    return d;
}

// Block: 256 threads = 8 rays x 32 threads; each thread 4 consecutive samples.
// 2048 blocks -> 8 blocks/CU -> 32 waves/CU (max occupancy) to hide
// LDS/shuffle/barrier latency (R6 evidence: kernel is stall-bound, not
// VALU-issue-bound). Weights packed to f16 pairs in LDS once per block;
// per-ray base (b1 + d@W2) folded into the layer-1 bias pair.
__global__ __launch_bounds__(256, 8) void nerf_render_kernel(
    const float* __restrict__ rays_o,   // [R,3]
    const float* __restrict__ rays_d,   // [R,3]
    const float* __restrict__ W1,       // [3,64]
    const float* __restrict__ W2,       // [3,64]
    const float* __restrict__ b1,       // [64]
    const float* __restrict__ w_sigma,  // [64]
    const float* __restrict__ W_color,  // [64,3]
    float* __restrict__ out_image,      // [R,3]
    float* __restrict__ out_depth,      // [R]
    float* __restrict__ out_weights,    // [R,128]
    float* __restrict__ out_wsum,       // [R]
    int R)
{
    // A[r][jp]: {w1x2, w1y2, w1z2, base2} per ray r, hidden-pair jp.
    __shared__ uint4 ldsA[RAYS_PER_BLOCK][33];   // stride-33 pad
    __shared__ uint4 ldsB[32];                   // {ws2, wcr2, wcg2, wcb2} per jp

    const int tid = threadIdx.x;

    // ---- cooperative LDS build: 256 A-entries over 256 threads ----
    {
        const int e  = tid;
        const int r  = e >> 5;
        const int jp = e & 31;
        const int j0 = jp * 2;
        int gray = blockIdx.x * RAYS_PER_BLOCK + r;
        if (gray >= R) gray = R - 1;
        const float dd0 = rays_d[gray * 3 + 0];
        const float dd1 = rays_d[gray * 3 + 1];
        const float dd2 = rays_d[gray * 3 + 2];
        const float2 w1x = *(const float2*)&W1[0 * HID + j0];
        const float2 w1y = *(const float2*)&W1[1 * HID + j0];
        const float2 w1z = *(const float2*)&W1[2 * HID + j0];
        const float2 w2x = *(const float2*)&W2[0 * HID + j0];
        const float2 w2y = *(const float2*)&W2[1 * HID + j0];
        const float2 w2z = *(const float2*)&W2[2 * HID + j0];
        const float2 bb  = *(const float2*)&b1[j0];
        const float bs0 = fmaf(dd0, w2x.x, fmaf(dd1, w2y.x, fmaf(dd2, w2z.x, bb.x)));
        const float bs1 = fmaf(dd0, w2x.y, fmaf(dd1, w2y.y, fmaf(dd2, w2z.y, bb.y)));
        uint4 v;
        v.x = pk_bits(w1x.x, w1x.y);
        v.y = pk_bits(w1y.x, w1y.y);
        v.z = pk_bits(w1z.x, w1z.y);
        v.w = pk_bits(bs0, bs1);
        ldsA[r][jp] = v;
    }
    if (tid < 32) {
        const int j0 = tid * 2;
        const float2 ws = *(const float2*)&w_sigma[j0];
        const float c00 = W_color[j0 * 3 + 0], c01 = W_color[j0 * 3 + 1], c02 = W_color[j0 * 3 + 2];
        const float c10 = W_color[j0 * 3 + 3], c11 = W_color[j0 * 3 + 4], c12 = W_color[j0 * 3 + 5];
        uint4 v;
        v.x = pk_bits(ws.x, ws.y);
        v.y = pk_bits(c00, c10);
        v.z = pk_bits(c01, c11);
        v.w = pk_bits(c02, c12);
        ldsB[tid] = v;
    }
    __syncthreads();

    const int r   = tid >> 5;        // ray within block (0..7)
    const int l   = tid & 31;        // lane within ray (0..31)
    int ray = blockIdx.x * RAYS_PER_BLOCK + r;
    const bool valid = (ray < R);
    if (!valid) ray = R - 1;

    const float o0 = rays_o[ray * 3 + 0];
    const float o1 = rays_o[ray * 3 + 1];
    const float o2 = rays_o[ray * 3 + 2];
    const float d0 = rays_d[ray * 3 + 0];
    const float d1 = rays_d[ray * 3 + 1];
    const float d2 = rays_d[ray * 3 + 2];

    // ---- near/far: cube AABB [-1,1]^3 ----
    const float inv0 = 1.0f / (d0 + 1e-15f);
    const float inv1 = 1.0f / (d1 + 1e-15f);
    const float inv2 = 1.0f / (d2 + 1e-15f);
    const float t0a = (-1.0f - o0) * inv0, t0b = (1.0f - o0) * inv0;
    const float t1a = (-1.0f - o1) * inv1, t1b = (1.0f - o1) * inv1;
    const float t2a = (-1.0f - o2) * inv2, t2b = (1.0f - o2) * inv2;
    float near = fmaxf(fmaxf(fminf(t0a, t0b), fminf(t1a, t1b)), fminf(t2a, t2b));
    float far  = fminf(fminf(fmaxf(t0a, t0b), fmaxf(t1a, t1b)), fmaxf(t2a, t2b));
    if (far < near) { near = 1e9f; far = 1e9f; }
    near = fmaxf(near, 0.05f);
    const float span = far - near;
    const float sample_dist = span * (1.0f / (NSTEPS - 1));

    // ---- sample points, duplicated into f16 pairs ----
    unsigned X0[SPT], X1[SPT], X2[SPT];
#pragma unroll
    for (int k = 0; k < SPT; k++) {
        const int s = l * SPT + k;
        const float t = (float)s * (1.0f / (NSTEPS - 1));
        const float z = fmaf(span, t, near);
        const float x0 = fminf(fmaxf(fmaf(d0, z, o0), -1.0f), 1.0f);
        const float x1 = fminf(fmaxf(fmaf(d1, z, o1), -1.0f), 1.0f);
        const float x2 = fminf(fmaxf(fmaf(d2, z, o2), -1.0f), 1.0f);
        X0[k] = pk_bits(x0, x0);
        X1[k] = pk_bits(x1, x1);
        X2[k] = pk_bits(x2, x2);
    }

    // ---- MLP over 32 hidden-unit pairs, f32 accumulators via dot2 ----
    float aS[SPT] = {0,0,0,0};
    float aR[SPT] = {0,0,0,0};
    float aG[SPT] = {0,0,0,0};
    float aB[SPT] = {0,0,0,0};

#pragma unroll 4
    for (int jp = 0; jp < 32; jp++) {
        const uint4 A  = ldsA[r][jp];
        const uint4 Bq = ldsB[jp];
#pragma unroll
        for (int k = 0; k < SPT; k++) {
            unsigned h = pk_fma(X0[k], A.x, pk_fma(X1[k], A.y, pk_fma(X2[k], A.z, A.w)));
            h = pk_relu(h);
            aS[k] = dot2acc(h, Bq.x, aS[k]);
            aR[k] = dot2acc(h, Bq.y, aR[k]);
            aG[k] = dot2acc(h, Bq.z, aG[k]);
            aB[k] = dot2acc(h, Bq.w, aB[k]);
        }
    }

    // ---- sigma -> alpha, thread-local transmittance ----
    float alpha[SPT], Tloc[SPT];
    float pl = 1.0f;
#pragma unroll
    for (int k = 0; k < SPT; k++) {
        const float x = aS[k];
        const float sig = fmaxf(x, 0.0f) + __logf(1.0f + __expf(-fabsf(x)));
        alpha[k] = 1.0f - __expf(-sample_dist * sig);
        Tloc[k] = pl;
        pl *= (1.0f - alpha[k] + 1e-15f);
    }

    // ---- exclusive scan of products across the 32 lanes of this ray ----
    float inc = pl;
#pragma unroll
    for (int dlt = 1; dlt < THREADS_PER_RAY; dlt <<= 1) {
        const float v = __shfl_up(inc, dlt, THREADS_PER_RAY);
        if (l >= dlt) inc *= v;
    }
    float excl = __shfl_up(inc, 1, THREADS_PER_RAY);
    if (l == 0) excl = 1.0f;

    // ---- weights, color, depth ----
    float w[SPT];
    float wsum = 0.f, dep = 0.f, im0 = 0.f, im1 = 0.f, im2 = 0.f;
#pragma unroll
    for (int k = 0; k < SPT; k++) {
        const int s = l * SPT + k;
        const float t = (float)s * (1.0f / (NSTEPS - 1));
        const float z = fmaf(span, t, near);
        const float T  = excl * Tloc[k];
        const float wt = alpha[k] * T;
        w[k] = wt;
        wsum += wt;
        dep  += wt * z;
        const float cr = 1.0f / (1.0f + __expf(-aR[k]));
        const float cg = 1.0f / (1.0f + __expf(-aG[k]));
        const float cb = 1.0f / (1.0f + __expf(-aB[k]));
        im0 += wt * cr;
        im1 += wt * cg;
        im2 += wt * cb;
    }

    if (valid) {
        *(float4*)&out_weights[(size_t)ray * NSTEPS + l * SPT] =
            make_float4(w[0], w[1], w[2], w[3]);
    }

    // ---- reduce across the ray's 32 lanes ----
#pragma unroll
    for (int dlt = THREADS_PER_RAY / 2; dlt >= 1; dlt >>= 1) {
        wsum += __shfl_down(wsum, dlt, THREADS_PER_RAY);
        dep  += __shfl_down(dep,  dlt, THREADS_PER_RAY);
        im0  += __shfl_down(im0,  dlt, THREADS_PER_RAY);
        im1  += __shfl_down(im1,  dlt, THREADS_PER_RAY);
        im2  += __shfl_down(im2,  dlt, THREADS_PER_RAY);
    }
    if (l == 0 && valid) {
        out_image[ray * 3 + 0] = im0;
        out_image[ray * 3 + 1] = im1;
        out_image[ray * 3 + 2] = im2;
        out_depth[ray] = dep;
        out_wsum[ray]  = wsum;
    }
}

extern "C" void kernel_launch(void* const* d_in, const int* in_sizes, int n_in,
                              void* d_out, int out_size, void* d_ws, size_t ws_size,
                              hipStream_t stream) {
    const float* rays_o  = (const float*)d_in[0];
    const float* rays_d  = (const float*)d_in[1];
    const float* W1      = (const float*)d_in[2];
    const float* W2      = (const float*)d_in[3];
    const float* b1      = (const float*)d_in[4];
    const float* w_sigma = (const float*)d_in[5];
    const float* W_color = (const float*)d_in[6];

    const int R = in_sizes[0] / 3;  // B*N rays

    float* out         = (float*)d_out;
    float* out_image   = out;                               // [R,3]
    float* out_depth   = out_image + (size_t)R * 3;         // [R]
    float* out_weights = out_depth + R;                     // [R,128]
    float* out_wsum    = out_weights + (size_t)R * NSTEPS;  // [R]

    const int blocks = (R + RAYS_PER_BLOCK - 1) / RAYS_PER_BLOCK;
    nerf_render_kernel<<<blocks, 256, 0, stream>>>(
        rays_o, rays_d, W1, W2, b1, w_sigma, W_color,
        out_image, out_depth, out_weights, out_wsum, R);
}

// Round 8
// 91.309 us; speedup vs baseline: 1.0103x; 1.0103x over previous
//
#include <hip/hip_runtime.h>
#include <math.h>

#define NSTEPS 128
#define HID 64
#define RAYS_PER_BLOCK 8
#define THREADS_PER_RAY 32
#define SPT 4   // samples per thread

// Packed-f16 ops via inline asm (VOP3P), f32 accumulate via v_dot2_f32_f16.
static __device__ __forceinline__ unsigned pk_bits(float a, float b) {
    auto v = __builtin_amdgcn_cvt_pkrtz(a, b);   // v_cvt_pkrtz_f16_f32
    return __builtin_bit_cast(unsigned, v);
}
static __device__ __forceinline__ unsigned pk_fma(unsigned a, unsigned b, unsigned c) {
    unsigned d;
    asm("v_pk_fma_f16 %0, %1, %2, %3" : "=v"(d) : "v"(a), "v"(b), "v"(c));
    return d;
}
static __device__ __forceinline__ unsigned pk_relu(unsigned a) {
    unsigned d;
    asm("v_pk_max_f16 %0, %1, 0" : "=v"(d) : "v"(a));
    return d;
}
static __device__ __forceinline__ float dot2acc(unsigned h, unsigned w, float acc) {
    float d;
    asm("v_dot2_f32_f16 %0, %1, %2, %3" : "=v"(d) : "v"(h), "v"(w), "v"(acc));
    return d;
}

// Key algebra: for z in [near,far] the sample point o + d*z is inside the
// AABB (far = exit), so clamp is a no-op for hit rays and a constant for
// miss rays. Thus x(s) = xn + (xf-xn)*(s/127) exactly, and the pre-relu
// activation is affine in s:  t_j(s) = u_j + s*g_j  with per-ray
//   u_j = xn.W1_j + d.W2_j + b_j,   g_j = ((xf-xn)/127).W1_j.
// Layer 1 collapses to one packed FMA per hidden-pair per sample.
__global__ __launch_bounds__(256, 8) void nerf_render_kernel(
    const float* __restrict__ rays_o,   // [R,3]
    const float* __restrict__ rays_d,   // [R,3]
    const float* __restrict__ W1,       // [3,64]
    const float* __restrict__ W2,       // [3,64]
    const float* __restrict__ b1,       // [64]
    const float* __restrict__ w_sigma,  // [64]
    const float* __restrict__ W_color,  // [64,3]
    float* __restrict__ out_image,      // [R,3]
    float* __restrict__ out_depth,      // [R]
    float* __restrict__ out_weights,    // [R,128]
    float* __restrict__ out_wsum,       // [R]
    int R)
{
    __shared__ uint2 ldsA[RAYS_PER_BLOCK][33];   // {u2, g2} per (ray, jp); padded
    __shared__ uint4 ldsB[32];                   // {ws2, wcr2, wcg2, wcb2} per jp

    const int tid = threadIdx.x;
    const int r   = tid >> 5;        // ray within block (0..7)
    const int l   = tid & 31;        // lane within ray / jp for the build (0..31)

    int ray = blockIdx.x * RAYS_PER_BLOCK + r;
    const bool valid = (ray < R);
    if (!valid) ray = R - 1;

    const float o0 = rays_o[ray * 3 + 0];
    const float o1 = rays_o[ray * 3 + 1];
    const float o2 = rays_o[ray * 3 + 2];
    const float d0 = rays_d[ray * 3 + 0];
    const float d1 = rays_d[ray * 3 + 1];
    const float d2 = rays_d[ray * 3 + 2];

    // ---- near/far: cube AABB [-1,1]^3 ----
    const float inv0 = 1.0f / (d0 + 1e-15f);
    const float inv1 = 1.0f / (d1 + 1e-15f);
    const float inv2 = 1.0f / (d2 + 1e-15f);
    const float t0a = (-1.0f - o0) * inv0, t0b = (1.0f - o0) * inv0;
    const float t1a = (-1.0f - o1) * inv1, t1b = (1.0f - o1) * inv1;
    const float t2a = (-1.0f - o2) * inv2, t2b = (1.0f - o2) * inv2;
    float near = fmaxf(fmaxf(fminf(t0a, t0b), fminf(t1a, t1b)), fminf(t2a, t2b));
    float far  = fminf(fminf(fmaxf(t0a, t0b), fmaxf(t1a, t1b)), fmaxf(t2a, t2b));
    if (far < near) { near = 1e9f; far = 1e9f; }
    near = fmaxf(near, 0.05f);
    const float span = far - near;
    const float sample_dist = span * (1.0f / (NSTEPS - 1));

    // Clamped endpoints (exact for hit rays; the constant point for misses).
    const float xn0 = fminf(fmaxf(fmaf(d0, near, o0), -1.0f), 1.0f);
    const float xn1 = fminf(fmaxf(fmaf(d1, near, o1), -1.0f), 1.0f);
    const float xn2 = fminf(fmaxf(fmaf(d2, near, o2), -1.0f), 1.0f);
    const float xf0 = fminf(fmaxf(fmaf(d0, far, o0), -1.0f), 1.0f);
    const float xf1 = fminf(fmaxf(fmaf(d1, far, o1), -1.0f), 1.0f);
    const float xf2 = fminf(fmaxf(fmaf(d2, far, o2), -1.0f), 1.0f);
    const float sx0 = (xf0 - xn0) * (1.0f / (NSTEPS - 1));
    const float sx1 = (xf1 - xn1) * (1.0f / (NSTEPS - 1));
    const float sx2 = (xf2 - xn2) * (1.0f / (NSTEPS - 1));

    // ---- cooperative LDS build: this thread fills (r, jp=l) ----
    {
        const int j0 = l * 2;
        const float2 w1x = *(const float2*)&W1[0 * HID + j0];
        const float2 w1y = *(const float2*)&W1[1 * HID + j0];
        const float2 w1z = *(const float2*)&W1[2 * HID + j0];
        const float2 w2x = *(const float2*)&W2[0 * HID + j0];
        const float2 w2y = *(const float2*)&W2[1 * HID + j0];
        const float2 w2z = *(const float2*)&W2[2 * HID + j0];
        const float2 bb  = *(const float2*)&b1[j0];
        const float u0 = fmaf(xn0, w1x.x, fmaf(xn1, w1y.x, fmaf(xn2, w1z.x,
                         fmaf(d0, w2x.x, fmaf(d1, w2y.x, fmaf(d2, w2z.x, bb.x))))));
        const float u1 = fmaf(xn0, w1x.y, fmaf(xn1, w1y.y, fmaf(xn2, w1z.y,
                         fmaf(d0, w2x.y, fmaf(d1, w2y.y, fmaf(d2, w2z.y, bb.y))))));
        const float g0 = fmaf(sx0, w1x.x, fmaf(sx1, w1y.x, sx2 * w1z.x));
        const float g1 = fmaf(sx0, w1x.y, fmaf(sx1, w1y.y, sx2 * w1z.y));
        uint2 v;
        v.x = pk_bits(u0, u1);
        v.y = pk_bits(g0, g1);
        ldsA[r][l] = v;
    }
    if (tid < 32) {
        const int j0 = tid * 2;
        const float2 ws = *(const float2*)&w_sigma[j0];
        const float c00 = W_color[j0 * 3 + 0], c01 = W_color[j0 * 3 + 1], c02 = W_color[j0 * 3 + 2];
        const float c10 = W_color[j0 * 3 + 3], c11 = W_color[j0 * 3 + 4], c12 = W_color[j0 * 3 + 5];
        uint4 v;
        v.x = pk_bits(ws.x, ws.y);
        v.y = pk_bits(c00, c10);
        v.z = pk_bits(c01, c11);
        v.w = pk_bits(c02, c12);
        ldsB[tid] = v;
    }
    __syncthreads();

    // ---- packed sample indices (integers, exact in f16) ----
    unsigned S[SPT];
#pragma unroll
    for (int k = 0; k < SPT; k++) {
        const float sv = (float)(l * SPT + k);
        S[k] = pk_bits(sv, sv);
    }

    // ---- MLP over 32 hidden-unit pairs: t = u + s*g, relu, 4x dot2 ----
    float aS[SPT] = {0,0,0,0};
    float aR[SPT] = {0,0,0,0};
    float aG[SPT] = {0,0,0,0};
    float aB[SPT] = {0,0,0,0};

#pragma unroll 8
    for (int jp = 0; jp < 32; jp++) {
        const uint2 A  = ldsA[r][jp];
        const uint4 Bq = ldsB[jp];
#pragma unroll
        for (int k = 0; k < SPT; k++) {
            const unsigned h = pk_relu(pk_fma(S[k], A.y, A.x));
            aS[k] = dot2acc(h, Bq.x, aS[k]);
            aR[k] = dot2acc(h, Bq.y, aR[k]);
            aG[k] = dot2acc(h, Bq.z, aG[k]);
            aB[k] = dot2acc(h, Bq.w, aB[k]);
        }
    }

    // ---- sigma -> alpha, thread-local transmittance ----
    float alpha[SPT], Tloc[SPT];
    float pl = 1.0f;
#pragma unroll
    for (int k = 0; k < SPT; k++) {
        const float x = aS[k];
        const float sig = fmaxf(x, 0.0f) + __logf(1.0f + __expf(-fabsf(x)));
        alpha[k] = 1.0f - __expf(-sample_dist * sig);
        Tloc[k] = pl;
        pl *= (1.0f - alpha[k] + 1e-15f);
    }

    // ---- exclusive scan of products across the 32 lanes of this ray ----
    float inc = pl;
#pragma unroll
    for (int dlt = 1; dlt < THREADS_PER_RAY; dlt <<= 1) {
        const float v = __shfl_up(inc, dlt, THREADS_PER_RAY);
        if (l >= dlt) inc *= v;
    }
    float excl = __shfl_up(inc, 1, THREADS_PER_RAY);
    if (l == 0) excl = 1.0f;

    // ---- weights, color, depth ----
    float w[SPT];
    float wsum = 0.f, dep = 0.f, im0 = 0.f, im1 = 0.f, im2 = 0.f;
#pragma unroll
    for (int k = 0; k < SPT; k++) {
        const int s = l * SPT + k;
        const float t = (float)s * (1.0f / (NSTEPS - 1));
        const float z = fmaf(span, t, near);
        const float T  = excl * Tloc[k];
        const float wt = alpha[k] * T;
        w[k] = wt;
        wsum += wt;
        dep  += wt * z;
        const float cr = 1.0f / (1.0f + __expf(-aR[k]));
        const float cg = 1.0f / (1.0f + __expf(-aG[k]));
        const float cb = 1.0f / (1.0f + __expf(-aB[k]));
        im0 += wt * cr;
        im1 += wt * cg;
        im2 += wt * cb;
    }

    if (valid) {
        *(float4*)&out_weights[(size_t)ray * NSTEPS + l * SPT] =
            make_float4(w[0], w[1], w[2], w[3]);
    }

    // ---- reduce across the ray's 32 lanes ----
#pragma unroll
    for (int dlt = THREADS_PER_RAY / 2; dlt >= 1; dlt >>= 1) {
        wsum += __shfl_down(wsum, dlt, THREADS_PER_RAY);
        dep  += __shfl_down(dep,  dlt, THREADS_PER_RAY);
        im0  += __shfl_down(im0,  dlt, THREADS_PER_RAY);
        im1  += __shfl_down(im1,  dlt, THREADS_PER_RAY);
        im2  += __shfl_down(im2,  dlt, THREADS_PER_RAY);
    }
    if (l == 0 && valid) {
        out_image[ray * 3 + 0] = im0;
        out_image[ray * 3 + 1] = im1;
        out_image[ray * 3 + 2] = im2;
        out_depth[ray] = dep;
        out_wsum[ray]  = wsum;
    }
}

extern "C" void kernel_launch(void* const* d_in, const int* in_sizes, int n_in,
                              void* d_out, int out_size, void* d_ws, size_t ws_size,
                              hipStream_t stream) {
    const float* rays_o  = (const float*)d_in[0];
    const float* rays_d  = (const float*)d_in[1];
    const float* W1      = (const float*)d_in[2];
    const float* W2      = (const float*)d_in[3];
    const float* b1      = (const float*)d_in[4];
    const float* w_sigma = (const float*)d_in[5];
    const float* W_color = (const float*)d_in[6];

    const int R = in_sizes[0] / 3;  // B*N rays

    float* out         = (float*)d_out;
    float* out_image   = out;                               // [R,3]
    float* out_depth   = out_image + (size_t)R * 3;         // [R]
    float* out_weights = out_depth + R;                     // [R,128]
    float* out_wsum    = out_weights + (size_t)R * NSTEPS;  // [R]

    const int blocks = (R + RAYS_PER_BLOCK - 1) / RAYS_PER_BLOCK;
    nerf_render_kernel<<<blocks, 256, 0, stream>>>(
        rays_o, rays_d, W1, W2, b1, w_sigma, W_color,
        out_image, out_depth, out_weights, out_wsum, R);
}

// Round 9
// 87.910 us; speedup vs baseline: 1.0494x; 1.0387x over previous
//
#include <hip/hip_runtime.h>
#include <math.h>

#define NSTEPS 128
#define HID 64
#define RAYS_PER_BLOCK 8
#define THREADS_PER_RAY 32
#define SPT 4   // samples per thread

// Packed-f16 ops via inline asm (VOP3P), f32 accumulate via v_dot2_f32_f16.
static __device__ __forceinline__ unsigned pk_bits(float a, float b) {
    auto v = __builtin_amdgcn_cvt_pkrtz(a, b);   // v_cvt_pkrtz_f16_f32
    return __builtin_bit_cast(unsigned, v);
}
static __device__ __forceinline__ unsigned pk_fma(unsigned a, unsigned b, unsigned c) {
    unsigned d;
    asm("v_pk_fma_f16 %0, %1, %2, %3" : "=v"(d) : "v"(a), "v"(b), "v"(c));
    return d;
}
static __device__ __forceinline__ unsigned pk_relu(unsigned a) {
    unsigned d;
    asm("v_pk_max_f16 %0, %1, 0" : "=v"(d) : "v"(a));
    return d;
}
// B-weight operand lives in an SGPR (uniform, s_load'ed): VOP3P may read one
// scalar source per instruction -- h and acc are the VGPR operands.
static __device__ __forceinline__ float dot2acc_s(unsigned h, unsigned w, float acc) {
    float d;
    asm("v_dot2_f32_f16 %0, %1, %2, %3" : "=v"(d) : "v"(h), "s"(w), "v"(acc));
    return d;
}

// Tiny prepack: 32 uint4 {ws2, wcr2, wcg2, wcb2} per hidden-pair into d_ws.
__global__ __launch_bounds__(64) void pack_b_kernel(
    const float* __restrict__ w_sigma, const float* __restrict__ W_color,
    uint4* __restrict__ bpk)
{
    const int jp = threadIdx.x;
    if (jp < 32) {
        const int j0 = jp * 2;
        const float2 ws = *(const float2*)&w_sigma[j0];
        const float c00 = W_color[j0 * 3 + 0], c01 = W_color[j0 * 3 + 1], c02 = W_color[j0 * 3 + 2];
        const float c10 = W_color[j0 * 3 + 3], c11 = W_color[j0 * 3 + 4], c12 = W_color[j0 * 3 + 5];
        uint4 v;
        v.x = pk_bits(ws.x, ws.y);
        v.y = pk_bits(c00, c10);
        v.z = pk_bits(c01, c11);
        v.w = pk_bits(c02, c12);
        bpk[jp] = v;
    }
}

// Layer-1 collapse (see R8): activation is affine in sample index s,
// t_j(s) = u_j + s*g_j with per-ray u,g. B-weights come from d_ws via
// uniform s_load -> SGPRs (no LDS, no VGPR cost).
__global__ __launch_bounds__(256, 8) void nerf_render_kernel(
    const float* __restrict__ rays_o,   // [R,3]
    const float* __restrict__ rays_d,   // [R,3]
    const float* __restrict__ W1,       // [3,64]
    const float* __restrict__ W2,       // [3,64]
    const float* __restrict__ b1,       // [64]
    const uint4* __restrict__ Bpk,      // [32] packed B-weights (d_ws)
    float* __restrict__ out_image,      // [R,3]
    float* __restrict__ out_depth,      // [R]
    float* __restrict__ out_weights,    // [R,128]
    float* __restrict__ out_wsum,       // [R]
    int R)
{
    __shared__ uint2 ldsA[RAYS_PER_BLOCK][33];   // {u2, g2} per (ray, jp); padded

    const int tid = threadIdx.x;
    const int r   = tid >> 5;        // ray within block (0..7)
    const int l   = tid & 31;        // lane within ray / jp for the build (0..31)

    int ray = blockIdx.x * RAYS_PER_BLOCK + r;
    const bool valid = (ray < R);
    if (!valid) ray = R - 1;

    const float o0 = rays_o[ray * 3 + 0];
    const float o1 = rays_o[ray * 3 + 1];
    const float o2 = rays_o[ray * 3 + 2];
    const float d0 = rays_d[ray * 3 + 0];
    const float d1 = rays_d[ray * 3 + 1];
    const float d2 = rays_d[ray * 3 + 2];

    // ---- near/far: cube AABB [-1,1]^3 ----
    const float inv0 = 1.0f / (d0 + 1e-15f);
    const float inv1 = 1.0f / (d1 + 1e-15f);
    const float inv2 = 1.0f / (d2 + 1e-15f);
    const float t0a = (-1.0f - o0) * inv0, t0b = (1.0f - o0) * inv0;
    const float t1a = (-1.0f - o1) * inv1, t1b = (1.0f - o1) * inv1;
    const float t2a = (-1.0f - o2) * inv2, t2b = (1.0f - o2) * inv2;
    float near = fmaxf(fmaxf(fminf(t0a, t0b), fminf(t1a, t1b)), fminf(t2a, t2b));
    float far  = fminf(fminf(fmaxf(t0a, t0b), fmaxf(t1a, t1b)), fmaxf(t2a, t2b));
    if (far < near) { near = 1e9f; far = 1e9f; }
    near = fmaxf(near, 0.05f);
    const float span = far - near;
    const float sample_dist = span * (1.0f / (NSTEPS - 1));

    // Clamped endpoints (exact for hit rays; the constant point for misses).
    const float xn0 = fminf(fmaxf(fmaf(d0, near, o0), -1.0f), 1.0f);
    const float xn1 = fminf(fmaxf(fmaf(d1, near, o1), -1.0f), 1.0f);
    const float xn2 = fminf(fmaxf(fmaf(d2, near, o2), -1.0f), 1.0f);
    const float xf0 = fminf(fmaxf(fmaf(d0, far, o0), -1.0f), 1.0f);
    const float xf1 = fminf(fmaxf(fmaf(d1, far, o1), -1.0f), 1.0f);
    const float xf2 = fminf(fmaxf(fmaf(d2, far, o2), -1.0f), 1.0f);
    const float sx0 = (xf0 - xn0) * (1.0f / (NSTEPS - 1));
    const float sx1 = (xf1 - xn1) * (1.0f / (NSTEPS - 1));
    const float sx2 = (xf2 - xn2) * (1.0f / (NSTEPS - 1));

    // ---- cooperative LDS build: this thread fills (r, jp=l) ----
    {
        const int j0 = l * 2;
        const float2 w1x = *(const float2*)&W1[0 * HID + j0];
        const float2 w1y = *(const float2*)&W1[1 * HID + j0];
        const float2 w1z = *(const float2*)&W1[2 * HID + j0];
        const float2 w2x = *(const float2*)&W2[0 * HID + j0];
        const float2 w2y = *(const float2*)&W2[1 * HID + j0];
        const float2 w2z = *(const float2*)&W2[2 * HID + j0];
        const float2 bb  = *(const float2*)&b1[j0];
        const float u0 = fmaf(xn0, w1x.x, fmaf(xn1, w1y.x, fmaf(xn2, w1z.x,
                         fmaf(d0, w2x.x, fmaf(d1, w2y.x, fmaf(d2, w2z.x, bb.x))))));
        const float u1 = fmaf(xn0, w1x.y, fmaf(xn1, w1y.y, fmaf(xn2, w1z.y,
                         fmaf(d0, w2x.y, fmaf(d1, w2y.y, fmaf(d2, w2z.y, bb.y))))));
        const float g0 = fmaf(sx0, w1x.x, fmaf(sx1, w1y.x, sx2 * w1z.x));
        const float g1 = fmaf(sx0, w1x.y, fmaf(sx1, w1y.y, sx2 * w1z.y));
        uint2 v;
        v.x = pk_bits(u0, u1);
        v.y = pk_bits(g0, g1);
        ldsA[r][l] = v;
    }
    __syncthreads();

    // ---- packed sample indices (integers, exact in f16) ----
    unsigned S[SPT];
#pragma unroll
    for (int k = 0; k < SPT; k++) {
        const float sv = (float)(l * SPT + k);
        S[k] = pk_bits(sv, sv);
    }

    // ---- MLP over 32 hidden-unit pairs: t = u + s*g, relu, 4x dot2 ----
    float aS[SPT] = {0,0,0,0};
    float aR[SPT] = {0,0,0,0};
    float aG[SPT] = {0,0,0,0};
    float aB[SPT] = {0,0,0,0};

#pragma unroll 8
    for (int jp = 0; jp < 32; jp++) {
        const uint2 A  = ldsA[r][jp];
        const uint4 Bq = Bpk[jp];    // uniform -> s_load_dwordx4 -> SGPRs
#pragma unroll
        for (int k = 0; k < SPT; k++) {
            const unsigned h = pk_relu(pk_fma(S[k], A.y, A.x));
            aS[k] = dot2acc_s(h, Bq.x, aS[k]);
            aR[k] = dot2acc_s(h, Bq.y, aR[k]);
            aG[k] = dot2acc_s(h, Bq.z, aG[k]);
            aB[k] = dot2acc_s(h, Bq.w, aB[k]);
        }
    }

    // ---- sigma -> alpha, thread-local transmittance ----
    float alpha[SPT], Tloc[SPT];
    float pl = 1.0f;
#pragma unroll
    for (int k = 0; k < SPT; k++) {
        const float x = aS[k];
        const float sig = fmaxf(x, 0.0f) + __logf(1.0f + __expf(-fabsf(x)));
        alpha[k] = 1.0f - __expf(-sample_dist * sig);
        Tloc[k] = pl;
        pl *= (1.0f - alpha[k] + 1e-15f);
    }

    // ---- exclusive scan of products across the 32 lanes of this ray ----
    float inc = pl;
#pragma unroll
    for (int dlt = 1; dlt < THREADS_PER_RAY; dlt <<= 1) {
        const float v = __shfl_up(inc, dlt, THREADS_PER_RAY);
        if (l >= dlt) inc *= v;
    }
    float excl = __shfl_up(inc, 1, THREADS_PER_RAY);
    if (l == 0) excl = 1.0f;

    // ---- weights, color, depth ----
    float w[SPT];
    float wsum = 0.f, dep = 0.f, im0 = 0.f, im1 = 0.f, im2 = 0.f;
#pragma unroll
    for (int k = 0; k < SPT; k++) {
        const int s = l * SPT + k;
        const float t = (float)s * (1.0f / (NSTEPS - 1));
        const float z = fmaf(span, t, near);
        const float T  = excl * Tloc[k];
        const float wt = alpha[k] * T;
        w[k] = wt;
        wsum += wt;
        dep  += wt * z;
        const float cr = 1.0f / (1.0f + __expf(-aR[k]));
        const float cg = 1.0f / (1.0f + __expf(-aG[k]));
        const float cb = 1.0f / (1.0f + __expf(-aB[k]));
        im0 += wt * cr;
        im1 += wt * cg;
        im2 += wt * cb;
    }

    if (valid) {
        *(float4*)&out_weights[(size_t)ray * NSTEPS + l * SPT] =
            make_float4(w[0], w[1], w[2], w[3]);
    }

    // ---- reduce across the ray's 32 lanes ----
#pragma unroll
    for (int dlt = THREADS_PER_RAY / 2; dlt >= 1; dlt >>= 1) {
        wsum += __shfl_down(wsum, dlt, THREADS_PER_RAY);
        dep  += __shfl_down(dep,  dlt, THREADS_PER_RAY);
        im0  += __shfl_down(im0,  dlt, THREADS_PER_RAY);
        im1  += __shfl_down(im1,  dlt, THREADS_PER_RAY);
        im2  += __shfl_down(im2,  dlt, THREADS_PER_RAY);
    }
    if (l == 0 && valid) {
        out_image[ray * 3 + 0] = im0;
        out_image[ray * 3 + 1] = im1;
        out_image[ray * 3 + 2] = im2;
        out_depth[ray] = dep;
        out_wsum[ray]  = wsum;
    }
}

extern "C" void kernel_launch(void* const* d_in, const int* in_sizes, int n_in,
                              void* d_out, int out_size, void* d_ws, size_t ws_size,
                              hipStream_t stream) {
    const float* rays_o  = (const float*)d_in[0];
    const float* rays_d  = (const float*)d_in[1];
    const float* W1      = (const float*)d_in[2];
    const float* W2      = (const float*)d_in[3];
    const float* b1      = (const float*)d_in[4];
    const float* w_sigma = (const float*)d_in[5];
    const float* W_color = (const float*)d_in[6];

    const int R = in_sizes[0] / 3;  // B*N rays

    float* out         = (float*)d_out;
    float* out_image   = out;                               // [R,3]
    float* out_depth   = out_image + (size_t)R * 3;         // [R]
    float* out_weights = out_depth + R;                     // [R,128]
    float* out_wsum    = out_weights + (size_t)R * NSTEPS;  // [R]

    uint4* bpk = (uint4*)d_ws;   // 512 B of scratch

    pack_b_kernel<<<1, 64, 0, stream>>>(w_sigma, W_color, bpk);

    const int blocks = (R + RAYS_PER_BLOCK - 1) / RAYS_PER_BLOCK;
    nerf_render_kernel<<<blocks, 256, 0, stream>>>(
        rays_o, rays_d, W1, W2, b1, bpk,
        out_image, out_depth, out_weights, out_wsum, R);
}